// Round 10
// baseline (150.323 us; speedup 1.0000x reference)
//
#include <hip/hip_runtime.h>
#include <stdint.h>

// Problem constants (fixed shapes from reference)
#define M_ROWS 6272   // 32*196
#define K_DIM  768
#define N_DIM  3072
#define BM 128
#define BN 256
#define BK 32
#define NITER (K_DIM / BK)   // 24 tiles -> 12 paired epochs

#define X_CHUNKS (M_ROWS * K_DIM / 8)   // 602112
#define W_CHUNKS (N_DIM * K_DIM / 8)    // 294912
#define X_BLOCKS (X_CHUNKS / 256)       // 2352
#define W_BLOCKS (W_CHUNKS / 256)       // 1152

#define GRID_X (N_DIM / BN)             // 12
#define GRID_Y (M_ROWS / BM)            // 49
#define NWG    (GRID_X * GRID_Y)        // 588

typedef unsigned short u16;
typedef __attribute__((ext_vector_type(8))) __bf16 bf16x8;
typedef __attribute__((ext_vector_type(4))) float f32x4;

__device__ __forceinline__ u16 f32_to_bf16(float f) {
    unsigned u = __float_as_uint(f);
    unsigned r = 0x7FFFu + ((u >> 16) & 1u);
    return (u16)((u + r) >> 16);
}

__device__ __forceinline__ unsigned pack2(float a, float b) {
    return (unsigned)f32_to_bf16(a) | ((unsigned)f32_to_bf16(b) << 16);
}

// Async global->LDS DMA, 16B per lane. LDS dest is wave-uniform base +
// lane*16 (hardware rule); global source is per-lane.
#define GLOAD16(gp, lp) __builtin_amdgcn_global_load_lds( \
    (const __attribute__((address_space(1))) void*)(gp),  \
    (__attribute__((address_space(3))) void*)(lp), 16, 0, 0)

// Fused prep (verified): blocks [0, X_BLOCKS) cast x fp32->bf16;
// blocks [X_BLOCKS, X_BLOCKS+W_BLOCKS) expand block-circulant W to bf16.
__global__ void prep_kernel(const float* __restrict__ x, const float* __restrict__ w,
                            u16* __restrict__ xb, u16* __restrict__ wb) {
    int b = blockIdx.x;
    if (b < X_BLOCKS) {
        int idx = b * 256 + threadIdx.x;
        const float4* xp = (const float4*)x + (size_t)idx * 2;
        float4 a = xp[0], c = xp[1];
        uint4 v;
        v.x = pack2(a.x, a.y);
        v.y = pack2(a.z, a.w);
        v.z = pack2(c.x, c.y);
        v.w = pack2(c.z, c.w);
        ((uint4*)xb)[idx] = v;
    } else {
        int idx = (b - X_BLOCKS) * 256 + threadIdx.x;
        int n    = idx / 96;          // output row [0,3072)
        int kc   = idx - n * 96;      // 8-elem chunk along K
        int kblk = n / 768;           // 0..3
        int o    = n - kblk * 768;    // 0..767
        int j    = kc / 24;           // 0..3
        int c8   = kc - j * 24;       // 0..23
        int i    = (kblk - j) & 3;    // (kblk - j) mod 4
        const float* src = w + (((size_t)i * 768 + o) * 192 + c8 * 8);
        float4 a = ((const float4*)src)[0];
        float4 c = ((const float4*)src)[1];
        uint4 v;
        v.x = pack2(a.x, a.y);
        v.y = pack2(a.z, a.w);
        v.z = pack2(c.x, c.y);
        v.w = pack2(c.z, c.w);
        ((uint4*)wb)[idx] = v;
    }
}

// C[m,n] = sum_k A[m,k]*B[n,k] + bias[n]; A,B bf16 row-major K-contig, C fp32.
//
// Round-10 change (ONLY): PAIRED EPOCHS. Two BK=32 tiles per barrier epoch
// (24 tiles -> 12 epochs), 6 LDS sub-buffers (144 KB). Per-epoch accounting
// at 1 block/CU: 48 ds_read_b128 (~576 cyc CU-wide) serialized before 128
// MFMA (~621 cyc) + fixed cost (vmcnt land, barrier, issue convoy) ~ 1700
// cyc/epoch observed. Pairing halves the fixed-cost count and lets sub-1's
// reads ride behind sub-0's MFMA drain. Residency unchanged (1 block/CU,
// same as R5's 72KB) -> clean A/B on epoch granularity alone.
//
// vmcnt ledger (12 loads per pair): prologue issues pairs 0,1 (24 out).
// Epoch e: reads pair e, issues pair e+2 (24 out), vmcnt(12) retires
// EXACTLY pair e+1 (pair e+2 rides). Never 0 until the tail. ISSUE at
// epoch e targets subs of pair e+2 == subs of pair e-1 (period 3), whose
// readers were certified drained by epoch e-1's lgkm(0)+barrier.
//
// Tile format / DMA mapping / XOR swizzle (conflicts=0, verified R0-R5),
// wave geometry (4 waves, 128x64, acc[8][4]), m204 XCD remap, epilogue:
// byte-identical to round 5.
__global__ __launch_bounds__(256, 2) void gemm_bt(
    const u16* __restrict__ A,    // [M_ROWS, K_DIM] bf16
    const u16* __restrict__ B,    // [N_DIM,  K_DIM] bf16
    const float* __restrict__ bias,
    float* __restrict__ C)
{
    __shared__ __align__(16) u16 As[6][BM * BK];   // 6 x 8 KB
    __shared__ __align__(16) u16 Bs[6][BN * BK];   // 6 x 16 KB  (144 KB total)

    // ---- XCD-aware bijective remap of the 1-D block id (row-major, R5) ----
    const int orig = blockIdx.x;
    const int xcd  = orig & 7;
    const int pos  = orig >> 3;
    const int q    = NWG >> 3;          // 73
    const int r    = NWG & 7;           // 4
    const int lin  = (xcd < r ? xcd * (q + 1) : r * (q + 1) + (xcd - r) * q) + pos;
    const int rowBlk = lin / GRID_X;    // 0..48
    const int colBlk = lin - rowBlk * GRID_X;

    const int rowBase = rowBlk * BM;
    const int colBase = colBlk * BN;

    const int tid    = threadIdx.x;
    const int wave   = tid >> 6;    // 0..3 -> 64-col slice each
    const int lane   = tid & 63;
    const int lane16 = lane & 15;
    const int quad   = lane >> 4;
    const int wc     = wave;        // wave col (0..3)

    // DMA source addressing (verified). Chunk c: row=c>>2, lds slot=c&3,
    // global k-slot = (c&3)^((row>>1)&3). Thread t owns chunks {t, t+256,
    // ...}: rows 64 apart, same swizzle class -> one base + row-stride.
    const int rA = tid >> 2;
    const int sA = (tid & 3) ^ ((rA >> 1) & 3);

    const uint4* Ag = (const uint4*)(A + (size_t)(rowBase + rA) * K_DIM + sA * 8);
    const uint4* Bg = (const uint4*)(B + (size_t)(colBase + rA) * K_DIM + sA * 8);
    const int rowStride = 64 * (K_DIM / 8);   // 6144 uint4 per 64 rows

    // DMA dest: wave-uniform base; HW adds lane*16.
    char* AsB = (char*)As + wave * 1024;
    char* BsB = (char*)Bs + wave * 1024;

#define ISSUE(g, b) do {                                                    \
        GLOAD16(Ag + (g) * 4,                 AsB + (b) * 8192);            \
        GLOAD16(Ag + (g) * 4 + rowStride,     AsB + (b) * 8192 + 4096);     \
        GLOAD16(Bg + (g) * 4,                 BsB + (b) * 16384);           \
        GLOAD16(Bg + (g) * 4 + rowStride,     BsB + (b) * 16384 + 4096);    \
        GLOAD16(Bg + (g) * 4 + 2 * rowStride, BsB + (b) * 16384 + 8192);    \
        GLOAD16(Bg + (g) * 4 + 3 * rowStride, BsB + (b) * 16384 + 12288);   \
    } while (0)

    // read-side swizzle (verified conflicts=0)
    const int swz  = (lane16 >> 1) & 3;
    const int slot = (quad ^ swz) * 8;
    int aoff[8], boff[4];
#pragma unroll
    for (int i = 0; i < 8; ++i)
        aoff[i] = (i * 16 + lane16) * BK + slot;
#pragma unroll
    for (int j = 0; j < 4; ++j)
        boff[j] = (wc * 64 + j * 16 + lane16) * BK + slot;

    f32x4 acc[8][4] = {};

#define DS_READS(cb)                                                        \
    _Pragma("unroll") for (int i = 0; i < 8; ++i)                           \
        af[i] = *(const bf16x8*)&As[cb][aoff[i]];                           \
    _Pragma("unroll") for (int j = 0; j < 4; ++j)                           \
        bfv[j] = *(const bf16x8*)&Bs[cb][boff[j]];

#define MFMA32()                                                            \
    __builtin_amdgcn_s_setprio(1);                                          \
    _Pragma("unroll") for (int i = 0; i < 8; ++i)                           \
    _Pragma("unroll") for (int j = 0; j < 4; ++j)                           \
        acc[i][j] = __builtin_amdgcn_mfma_f32_16x16x32_bf16(                \
            af[i], bfv[j], acc[i][j], 0, 0, 0);                             \
    __builtin_amdgcn_s_setprio(0);

#define SUBTILE(cb) {                                                       \
        bf16x8 af[8], bfv[4];                                               \
        DS_READS(cb)                                                        \
        MFMA32()                                                            \
    }

    // steady epoch: read pair at subs {s0,s0+1}, issue tiles g,g+1 into
    // subs {fb,fb+1}, counted vmcnt(12) retires pair e+1, single barrier.
#define EPOCH(s0, fb, g) {                                                  \
        { bf16x8 af[8], bfv[4];                                             \
          DS_READS(s0)                                                      \
          ISSUE((g), (fb)); ISSUE((g) + 1, (fb) + 1);                       \
          MFMA32() }                                                        \
        SUBTILE((s0) + 1)                                                   \
        asm volatile("s_waitcnt vmcnt(12)" ::: "memory");                   \
        asm volatile("s_waitcnt lgkmcnt(0)\n\ts_barrier" ::: "memory");     \
    }

#define EPOCH_DRAIN(s0) {                                                   \
        SUBTILE(s0)                                                         \
        SUBTILE((s0) + 1)                                                   \
        asm volatile("s_waitcnt vmcnt(0)" ::: "memory");                    \
        asm volatile("s_waitcnt lgkmcnt(0)\n\ts_barrier" ::: "memory");     \
    }

#define EPOCH_LAST(s0) {                                                    \
        SUBTILE(s0)                                                         \
        SUBTILE((s0) + 1)                                                   \
    }

    // prologue: pairs 0 (subs 0,1) and 1 (subs 2,3) in flight; land pair 0
    ISSUE(0, 0); ISSUE(1, 1);
    ISSUE(2, 2); ISSUE(3, 3);
    asm volatile("s_waitcnt vmcnt(12)\n\ts_barrier" ::: "memory");

    // epochs 0..8 (sub-buffer pattern period 3), each reads pair e
    // (tiles 2e,2e+1) and issues pair e+2 (tiles 2e+4,2e+5)
    for (int k6 = 0; k6 < 18; k6 += 6) {
        EPOCH(0, 4, k6 + 4);
        EPOCH(2, 0, k6 + 6);
        EPOCH(4, 2, k6 + 8);
    }
    EPOCH(0, 4, 22);    // epoch 9: reads tiles 18,19; issues 22,23
    EPOCH_DRAIN(2);     // epoch 10: reads tiles 20,21; lands pair 11
    EPOCH_LAST(4);      // epoch 11: reads tiles 22,23; compute only

    // epilogue: C[row][col] = acc + bias[col]  (verified layout)
    float bv[4];
#pragma unroll
    for (int j = 0; j < 4; ++j)
        bv[j] = bias[colBase + wc * 64 + j * 16 + lane16];
#pragma unroll
    for (int i = 0; i < 8; ++i) {
        int row0 = rowBase + i * 16 + quad * 4;
#pragma unroll
        for (int r2 = 0; r2 < 4; ++r2) {
            float* cp = C + (size_t)(row0 + r2) * N_DIM + colBase + wc * 64 + lane16;
#pragma unroll
            for (int j = 0; j < 4; ++j)
                cp[j * 16] = acc[i][j][r2] + bv[j];
        }
    }
#undef ISSUE
#undef DS_READS
#undef MFMA32
#undef SUBTILE
#undef EPOCH
#undef EPOCH_DRAIN
#undef EPOCH_LAST
}

extern "C" void kernel_launch(void* const* d_in, const int* in_sizes, int n_in,
                              void* d_out, int out_size, void* d_ws, size_t ws_size,
                              hipStream_t stream) {
    const float* x    = (const float*)d_in[0];
    const float* w    = (const float*)d_in[1];
    const float* bias = (const float*)d_in[2];
    float* out = (float*)d_out;

    u16* xb = (u16*)d_ws;                                       // 9,633,792 B
    u16* wb = (u16*)((char*)d_ws + (size_t)M_ROWS * K_DIM * 2); // +4,718,592 B

    hipLaunchKernelGGL(prep_kernel, dim3(X_BLOCKS + W_BLOCKS), dim3(256),
                       0, stream, x, w, xb, wb);
    hipLaunchKernelGGL(gemm_bt, dim3(NWG), dim3(256),
                       0, stream, xb, wb, bias, out);
}